// Round 1
// baseline (128.654 us; speedup 1.0000x reference)
//
#include <hip/hip_runtime.h>
#include <hip/hip_bf16.h>

#define NROWS 8192
#define HALF_N 4096
#define KD 512
#define TILE 128
#define BK 64
#define TEMP_INV 2.0f

typedef __attribute__((ext_vector_type(8))) short bf16x8;
typedef __attribute__((ext_vector_type(4))) float f32x4;

__device__ __forceinline__ unsigned short f2bf(float f) {
    unsigned int u = __float_as_uint(f);
    u = (u + 0x7FFFu + ((u >> 16) & 1u)) >> 16;   // round-to-nearest-even
    return (unsigned short)u;
}

// Kernel 1: row-normalize f32 -> bf16, and zero the accumulators (sumexp, out).
__global__ __launch_bounds__(256) void normalize_kernel(const float* __restrict__ X,
                                                        unsigned short* __restrict__ XN,
                                                        float* __restrict__ sumexp,
                                                        float* __restrict__ out) {
    const int row = blockIdx.x;
    const int tid = threadIdx.x;
    const int gz = row * 256 + tid;
    if (gz < NROWS) sumexp[gz] = 0.0f;
    if (gz == 0) out[0] = 0.0f;

    const float2 v = reinterpret_cast<const float2*>(X + (size_t)row * KD)[tid];
    float ss = v.x * v.x + v.y * v.y;
    #pragma unroll
    for (int off = 32; off >= 1; off >>= 1) ss += __shfl_xor(ss, off);
    __shared__ float wss[4];
    if ((tid & 63) == 0) wss[tid >> 6] = ss;
    __syncthreads();
    const float tot = wss[0] + wss[1] + wss[2] + wss[3];
    const float scale = 1.0f / fmaxf(sqrtf(tot), 1e-6f);
    ushort2 o;
    o.x = f2bf(v.x * scale);
    o.y = f2bf(v.y * scale);
    reinterpret_cast<ushort2*>(XN + (size_t)row * KD)[tid] = o;
}

// Kernel 2: fused S = XN*XN^T tile GEMM (bf16 MFMA) + exp + row-sum + pos-logit.
// m97 structure: 128x128 tile, BK=64, 4 waves (2x2 of 64x64), global_load_lds w=16,
// XOR chunk swizzle (rule 21: linear LDS dest + inverse-swizzled global src + swizzled read).
__global__ __launch_bounds__(256) void gemm_fused_kernel(const unsigned short* __restrict__ XN,
                                                         float* __restrict__ sumexp,
                                                         float* __restrict__ poslogit) {
    __shared__ __align__(16) unsigned short Abuf[TILE * BK];
    __shared__ __align__(16) unsigned short Bbuf[TILE * BK];
    __shared__ float rowsum[TILE];

    const int tid  = threadIdx.x;
    const int lane = tid & 63;
    const int wid  = tid >> 6;          // 0..3
    const int wr   = wid >> 1;          // wave row (0/1)
    const int wc   = wid & 1;           // wave col (0/1)
    const int colBase = blockIdx.x * TILE;
    const int rowBase = blockIdx.y * TILE;
    const int l15 = lane & 15;
    const int l4  = lane >> 4;

    f32x4 acc[4][4] = {};

    for (int kt = 0; kt < KD / BK; ++kt) {
        const int kBase = kt * BK;
        // Stage A,B tiles: 1024 x 16B chunks, 1 KB per wave-call, 4 calls/wave/operand.
        // LDS chunk L holds global chunk (row, (L&7)^(row&7)) -> linear dest, permuted src.
        #pragma unroll
        for (int i = 0; i < 4; ++i) {
            const int L = (i * 4 + wid) * 64 + lane;
            const int r = L >> 3;
            const int src = (L & 7) ^ (r & 7);
            const unsigned short* gA = XN + (size_t)(rowBase + r) * KD + kBase + src * 8;
            const unsigned short* gB = XN + (size_t)(colBase + r) * KD + kBase + src * 8;
            __builtin_amdgcn_global_load_lds((const __attribute__((address_space(1))) void*)gA,
                                             (__attribute__((address_space(3))) void*)(Abuf + (i * 4 + wid) * 512),
                                             16, 0, 0);
            __builtin_amdgcn_global_load_lds((const __attribute__((address_space(1))) void*)gB,
                                             (__attribute__((address_space(3))) void*)(Bbuf + (i * 4 + wid) * 512),
                                             16, 0, 0);
        }
        __syncthreads();   // drains vmcnt; staged data visible

        #pragma unroll
        for (int kk = 0; kk < 2; ++kk) {
            bf16x8 aF[4], bF[4];
            #pragma unroll
            for (int m = 0; m < 4; ++m) {
                const int r = wr * 64 + m * 16 + l15;
                const int slot = (kk * 4 + l4) ^ (r & 7);
                aF[m] = *reinterpret_cast<const bf16x8*>(&Abuf[r * 64 + slot * 8]);
            }
            #pragma unroll
            for (int n = 0; n < 4; ++n) {
                const int r = wc * 64 + n * 16 + l15;
                const int slot = (kk * 4 + l4) ^ (r & 7);
                bF[n] = *reinterpret_cast<const bf16x8*>(&Bbuf[r * 64 + slot * 8]);
            }
            #pragma unroll
            for (int m = 0; m < 4; ++m)
                #pragma unroll
                for (int n = 0; n < 4; ++n)
                    acc[m][n] = __builtin_amdgcn_mfma_f32_16x16x32_bf16(aF[m], bF[n], acc[m][n], 0, 0, 0);
        }
        __syncthreads();   // before next k-step overwrites LDS
    }

    // Epilogue: s = acc*2; skip diagonal; accumulate per-row sum(exp); grab pos logit.
    // C/D mapping: col = lane&15, row = (lane>>4)*4 + reg  (S symmetric -> transpose-safe)
    if (tid < TILE) rowsum[tid] = 0.0f;
    __syncthreads();

    #pragma unroll
    for (int m = 0; m < 4; ++m) {
        #pragma unroll
        for (int r = 0; r < 4; ++r) {
            const int row_l = wr * 64 + m * 16 + l4 * 4 + r;
            const int grow = rowBase + row_l;
            const int prow = grow < HALF_N ? grow + HALF_N : grow - HALF_N;
            float p = 0.0f;
            #pragma unroll
            for (int n = 0; n < 4; ++n) {
                const int gcol = colBase + wc * 64 + n * 16 + l15;
                const float s = acc[m][n][r] * TEMP_INV;
                if (gcol != grow) p += __expf(s);
                if (gcol == prow) poslogit[grow] = s;   // unique writer per row
            }
            // reduce across the 16 lanes sharing this row (low-4 lane bits)
            p += __shfl_xor(p, 1);
            p += __shfl_xor(p, 2);
            p += __shfl_xor(p, 4);
            p += __shfl_xor(p, 8);
            if (l15 == 0) atomicAdd(&rowsum[row_l], p);   // LDS atomic
        }
    }
    __syncthreads();
    if (tid < TILE) atomicAdd(&sumexp[rowBase + tid], rowsum[tid]);  // 1 global atomic/row/block
}

// Kernel 3: loss = sum_i log(sumexp_i) - poslogit_i
__global__ __launch_bounds__(256) void finalize_kernel(const float* __restrict__ sumexp,
                                                       const float* __restrict__ poslogit,
                                                       float* __restrict__ out) {
    const int i = blockIdx.x * 256 + threadIdx.x;
    float li = logf(sumexp[i]) - poslogit[i];
    #pragma unroll
    for (int off = 32; off >= 1; off >>= 1) li += __shfl_xor(li, off);
    __shared__ float wss[4];
    if ((threadIdx.x & 63) == 0) wss[threadIdx.x >> 6] = li;
    __syncthreads();
    if (threadIdx.x == 0) atomicAdd(out, wss[0] + wss[1] + wss[2] + wss[3]);
}

extern "C" void kernel_launch(void* const* d_in, const int* in_sizes, int n_in,
                              void* d_out, int out_size, void* d_ws, size_t ws_size,
                              hipStream_t stream) {
    const float* X = (const float*)d_in[0];
    float* out = (float*)d_out;

    unsigned short* XN = (unsigned short*)d_ws;                       // 8 MB bf16
    float* sumexp   = (float*)((char*)d_ws + (size_t)NROWS * KD * 2); // 32 KB
    float* poslogit = sumexp + NROWS;                                 // 32 KB

    normalize_kernel<<<NROWS, 256, 0, stream>>>(X, XN, sumexp, out);
    dim3 grid(NROWS / TILE, NROWS / TILE);
    gemm_fused_kernel<<<grid, 256, 0, stream>>>(XN, sumexp, poslogit);
    finalize_kernel<<<NROWS / 256, 256, 0, stream>>>(sumexp, poslogit, out);
}

// Round 2
// 105.750 us; speedup vs baseline: 1.2166x; 1.2166x over previous
//
#include <hip/hip_runtime.h>
#include <hip/hip_bf16.h>

#define NROWS 8192
#define HALF_N 4096
#define KD 512
#define TILE 128
#define BK 64
#define TEMP_INV 2.0f

typedef __attribute__((ext_vector_type(8))) short bf16x8;
typedef __attribute__((ext_vector_type(4))) float f32x4;

__device__ __forceinline__ unsigned short f2bf(float f) {
    unsigned int u = __float_as_uint(f);
    u = (u + 0x7FFFu + ((u >> 16) & 1u)) >> 16;   // round-to-nearest-even
    return (unsigned short)u;
}

// Kernel 1: row-normalize f32 -> bf16, and zero the accumulators (sumexp, out).
__global__ __launch_bounds__(256) void normalize_kernel(const float* __restrict__ X,
                                                        unsigned short* __restrict__ XN,
                                                        float* __restrict__ sumexp,
                                                        float* __restrict__ out) {
    const int row = blockIdx.x;
    const int tid = threadIdx.x;
    const int gz = row * 256 + tid;
    if (gz < NROWS) sumexp[gz] = 0.0f;
    if (gz == 0) out[0] = 0.0f;

    const float2 v = reinterpret_cast<const float2*>(X + (size_t)row * KD)[tid];
    float ss = v.x * v.x + v.y * v.y;
    #pragma unroll
    for (int off = 32; off >= 1; off >>= 1) ss += __shfl_xor(ss, off);
    __shared__ float wss[4];
    if ((tid & 63) == 0) wss[tid >> 6] = ss;
    __syncthreads();
    const float tot = wss[0] + wss[1] + wss[2] + wss[3];
    const float scale = 1.0f / fmaxf(sqrtf(tot), 1e-6f);
    ushort2 o;
    o.x = f2bf(v.x * scale);
    o.y = f2bf(v.y * scale);
    reinterpret_cast<ushort2*>(XN + (size_t)row * KD)[tid] = o;
}

// Kernel 2: fused S = XN*XN^T tile GEMM (bf16 MFMA) + exp + row/col sums + pos logits.
// SYMMETRIC: only upper-triangle blocks (by >= bx is skipped when bx < by).
// Off-diagonal blocks contribute their exp() values to BOTH row sums and
// (transposed) column sums. Pos-pair entries are all strictly upper-triangle
// (col = row +/- 4096 => block offset 32); the holding lane writes both
// poslogit[row] and poslogit[col] (pos is an involution).
__global__ __launch_bounds__(256) void gemm_fused_kernel(const unsigned short* __restrict__ XN,
                                                         float* __restrict__ sumexp,
                                                         float* __restrict__ poslogit) {
    if (blockIdx.x < blockIdx.y) return;   // lower triangle: mirror handled by (y,x)

    __shared__ __align__(16) unsigned short Abuf[TILE * BK];
    __shared__ __align__(16) unsigned short Bbuf[TILE * BK];
    __shared__ float rowsum[TILE];
    __shared__ float colsum[TILE];

    const int tid  = threadIdx.x;
    const int lane = tid & 63;
    const int wid  = tid >> 6;          // 0..3
    const int wr   = wid >> 1;          // wave row (0/1)
    const int wc   = wid & 1;           // wave col (0/1)
    const int colBase = blockIdx.x * TILE;
    const int rowBase = blockIdx.y * TILE;
    const bool offdiag = (colBase != rowBase);
    const int l15 = lane & 15;
    const int l4  = lane >> 4;

    f32x4 acc[4][4] = {};

    for (int kt = 0; kt < KD / BK; ++kt) {
        const int kBase = kt * BK;
        // Stage A,B tiles: 1024 x 16B chunks each; linear LDS dest + XOR-permuted
        // global source (rule 21), matching swizzled ds_read below.
        #pragma unroll
        for (int i = 0; i < 4; ++i) {
            const int L = (i * 4 + wid) * 64 + lane;
            const int r = L >> 3;
            const int src = (L & 7) ^ (r & 7);
            const unsigned short* gA = XN + (size_t)(rowBase + r) * KD + kBase + src * 8;
            const unsigned short* gB = XN + (size_t)(colBase + r) * KD + kBase + src * 8;
            __builtin_amdgcn_global_load_lds((const __attribute__((address_space(1))) void*)gA,
                                             (__attribute__((address_space(3))) void*)(Abuf + (i * 4 + wid) * 512),
                                             16, 0, 0);
            __builtin_amdgcn_global_load_lds((const __attribute__((address_space(1))) void*)gB,
                                             (__attribute__((address_space(3))) void*)(Bbuf + (i * 4 + wid) * 512),
                                             16, 0, 0);
        }
        __syncthreads();   // drains vmcnt; staged data visible

        #pragma unroll
        for (int kk = 0; kk < 2; ++kk) {
            bf16x8 aF[4], bF[4];
            #pragma unroll
            for (int m = 0; m < 4; ++m) {
                const int r = wr * 64 + m * 16 + l15;
                const int slot = (kk * 4 + l4) ^ (r & 7);
                aF[m] = *reinterpret_cast<const bf16x8*>(&Abuf[r * 64 + slot * 8]);
            }
            #pragma unroll
            for (int n = 0; n < 4; ++n) {
                const int r = wc * 64 + n * 16 + l15;
                const int slot = (kk * 4 + l4) ^ (r & 7);
                bF[n] = *reinterpret_cast<const bf16x8*>(&Bbuf[r * 64 + slot * 8]);
            }
            #pragma unroll
            for (int m = 0; m < 4; ++m)
                #pragma unroll
                for (int n = 0; n < 4; ++n)
                    acc[m][n] = __builtin_amdgcn_mfma_f32_16x16x32_bf16(aF[m], bF[n], acc[m][n], 0, 0, 0);
        }
        __syncthreads();   // before next k-step overwrites LDS
    }

    // Epilogue. C/D mapping: col = lane&15, row = (lane>>4)*4 + reg.
    if (tid < TILE) { rowsum[tid] = 0.0f; colsum[tid] = 0.0f; }
    __syncthreads();

    float cs[4] = {0.0f, 0.0f, 0.0f, 0.0f};   // per-n column partials (col = l15 fixed)
    #pragma unroll
    for (int m = 0; m < 4; ++m) {
        #pragma unroll
        for (int r = 0; r < 4; ++r) {
            const int row_l = wr * 64 + m * 16 + l4 * 4 + r;
            const int grow = rowBase + row_l;
            const int prow = grow < HALF_N ? grow + HALF_N : grow - HALF_N;
            float p = 0.0f;
            #pragma unroll
            for (int n = 0; n < 4; ++n) {
                const int gcol = colBase + wc * 64 + n * 16 + l15;
                const float s = acc[m][n][r] * TEMP_INV;
                const float e = (gcol != grow) ? __expf(s) : 0.0f;
                p += e;
                cs[n] += e;
                if (gcol == prow) {            // strictly upper-triangle only
                    poslogit[grow] = s;
                    poslogit[gcol] = s;        // mirrored entry (pos involution)
                }
            }
            // reduce across the 16 lanes sharing this row (low-4 lane bits)
            p += __shfl_xor(p, 1);
            p += __shfl_xor(p, 2);
            p += __shfl_xor(p, 4);
            p += __shfl_xor(p, 8);
            if (l15 == 0) atomicAdd(&rowsum[row_l], p);   // LDS atomic
        }
    }
    if (offdiag) {
        #pragma unroll
        for (int n = 0; n < 4; ++n) {
            float c = cs[n];
            c += __shfl_xor(c, 16);
            c += __shfl_xor(c, 32);
            if (l4 == 0) atomicAdd(&colsum[wc * 64 + n * 16 + l15], c);
        }
    }
    __syncthreads();
    if (tid < TILE) {
        atomicAdd(&sumexp[rowBase + tid], rowsum[tid]);            // 1 global atomic/row/block
        if (offdiag) atomicAdd(&sumexp[colBase + tid], colsum[tid]); // transposed contribution
    }
}

// Kernel 3: loss = sum_i log(sumexp_i) - poslogit_i
__global__ __launch_bounds__(256) void finalize_kernel(const float* __restrict__ sumexp,
                                                       const float* __restrict__ poslogit,
                                                       float* __restrict__ out) {
    const int i = blockIdx.x * 256 + threadIdx.x;
    float li = logf(sumexp[i]) - poslogit[i];
    #pragma unroll
    for (int off = 32; off >= 1; off >>= 1) li += __shfl_xor(li, off);
    __shared__ float wss[4];
    if ((threadIdx.x & 63) == 0) wss[threadIdx.x >> 6] = li;
    __syncthreads();
    if (threadIdx.x == 0) atomicAdd(out, wss[0] + wss[1] + wss[2] + wss[3]);
}

extern "C" void kernel_launch(void* const* d_in, const int* in_sizes, int n_in,
                              void* d_out, int out_size, void* d_ws, size_t ws_size,
                              hipStream_t stream) {
    const float* X = (const float*)d_in[0];
    float* out = (float*)d_out;

    unsigned short* XN = (unsigned short*)d_ws;                       // 8 MB bf16
    float* sumexp   = (float*)((char*)d_ws + (size_t)NROWS * KD * 2); // 32 KB
    float* poslogit = sumexp + NROWS;                                 // 32 KB

    normalize_kernel<<<NROWS, 256, 0, stream>>>(X, XN, sumexp, out);
    dim3 grid(NROWS / TILE, NROWS / TILE);
    gemm_fused_kernel<<<grid, 256, 0, stream>>>(XN, sumexp, poslogit);
    finalize_kernel<<<NROWS / 256, 256, 0, stream>>>(sumexp, poslogit, out);
}

// Round 3
// 91.709 us; speedup vs baseline: 1.4028x; 1.1531x over previous
//
#include <hip/hip_runtime.h>
#include <hip/hip_bf16.h>
#include <math.h>

#define NROWS 8192
#define HALF_N 4096
#define KD 512
#define TILE 128
#define BK 64
#define TEMP_INV 2.0f
#define NBLK 64                   // NROWS / TILE
#define NTRI 2080                 // NBLK*(NBLK+1)/2 upper-triangle blocks

typedef __attribute__((ext_vector_type(8))) short bf16x8;
typedef __attribute__((ext_vector_type(4))) float f32x4;

__device__ __forceinline__ unsigned short f2bf(float f) {
    unsigned int u = __float_as_uint(f);
    u = (u + 0x7FFFu + ((u >> 16) & 1u)) >> 16;   // round-to-nearest-even
    return (unsigned short)u;
}

// Kernel 1: row-normalize f32 -> bf16, and zero the accumulators (sumexp, out).
__global__ __launch_bounds__(256) void normalize_kernel(const float* __restrict__ X,
                                                        unsigned short* __restrict__ XN,
                                                        float* __restrict__ sumexp,
                                                        float* __restrict__ out) {
    const int row = blockIdx.x;
    const int tid = threadIdx.x;
    const int gz = row * 256 + tid;
    if (gz < NROWS) sumexp[gz] = 0.0f;
    if (gz == 0) out[0] = 0.0f;

    const float2 v = reinterpret_cast<const float2*>(X + (size_t)row * KD)[tid];
    float ss = v.x * v.x + v.y * v.y;
    #pragma unroll
    for (int off = 32; off >= 1; off >>= 1) ss += __shfl_xor(ss, off);
    __shared__ float wss[4];
    if ((tid & 63) == 0) wss[tid >> 6] = ss;
    __syncthreads();
    const float tot = wss[0] + wss[1] + wss[2] + wss[3];
    const float scale = 1.0f / fmaxf(sqrtf(tot), 1e-6f);
    ushort2 o;
    o.x = f2bf(v.x * scale);
    o.y = f2bf(v.y * scale);
    reinterpret_cast<ushort2*>(XN + (size_t)row * KD)[tid] = o;
}

// Kernel 2: fused S = XN*XN^T tile GEMM (bf16 MFMA) + exp + row/col sums + pos logits.
// 1D grid of exactly the NTRI upper-triangle blocks (load-balanced: every
// dispatched block does full work; no dead blocks, no front-loaded tail).
// Off-diagonal blocks contribute exp() values to BOTH row sums and column sums.
__global__ __launch_bounds__(256) void gemm_fused_kernel(const unsigned short* __restrict__ XN,
                                                         float* __restrict__ sumexp,
                                                         float* __restrict__ poslogit) {
    // Bijective XCD swizzle (NTRI % 8 == 0): each XCD gets 260 consecutive
    // triangular indices -> consecutive blocks share the A row-panel in its L2.
    const int b = (blockIdx.x & 7) * (NTRI / 8) + (blockIdx.x >> 3);

    // Decode b -> (bi <= bj): row bi starts at offset(bi) = bi*(129-bi)/2.
    int bi = (int)(64.5f - sqrtf(64.5f * 64.5f - 2.0f * (float)b));
    while ((bi + 1) * (129 - (bi + 1)) / 2 <= b) ++bi;   // float-ulp fixup
    while (bi * (129 - bi) / 2 > b) --bi;
    const int bj = bi + (b - bi * (129 - bi) / 2);

    __shared__ __align__(16) unsigned short Abuf[TILE * BK];
    __shared__ __align__(16) unsigned short Bbuf[TILE * BK];
    __shared__ float rowsum[TILE];
    __shared__ float colsum[TILE];

    const int tid  = threadIdx.x;
    const int lane = tid & 63;
    const int wid  = tid >> 6;          // 0..3
    const int wr   = wid >> 1;          // wave row (0/1)
    const int wc   = wid & 1;           // wave col (0/1)
    const int rowBase = bi * TILE;
    const int colBase = bj * TILE;
    const bool offdiag = (colBase != rowBase);
    const int l15 = lane & 15;
    const int l4  = lane >> 4;

    f32x4 acc[4][4] = {};

    for (int kt = 0; kt < KD / BK; ++kt) {
        const int kBase = kt * BK;
        // Stage A,B tiles: 1024 x 16B chunks each; linear LDS dest + XOR-permuted
        // global source (rule 21), matching swizzled ds_read below.
        #pragma unroll
        for (int i = 0; i < 4; ++i) {
            const int L = (i * 4 + wid) * 64 + lane;
            const int r = L >> 3;
            const int src = (L & 7) ^ (r & 7);
            const unsigned short* gA = XN + (size_t)(rowBase + r) * KD + kBase + src * 8;
            const unsigned short* gB = XN + (size_t)(colBase + r) * KD + kBase + src * 8;
            __builtin_amdgcn_global_load_lds((const __attribute__((address_space(1))) void*)gA,
                                             (__attribute__((address_space(3))) void*)(Abuf + (i * 4 + wid) * 512),
                                             16, 0, 0);
            __builtin_amdgcn_global_load_lds((const __attribute__((address_space(1))) void*)gB,
                                             (__attribute__((address_space(3))) void*)(Bbuf + (i * 4 + wid) * 512),
                                             16, 0, 0);
        }
        __syncthreads();   // drains vmcnt; staged data visible

        #pragma unroll
        for (int kk = 0; kk < 2; ++kk) {
            bf16x8 aF[4], bF[4];
            #pragma unroll
            for (int m = 0; m < 4; ++m) {
                const int r = wr * 64 + m * 16 + l15;
                const int slot = (kk * 4 + l4) ^ (r & 7);
                aF[m] = *reinterpret_cast<const bf16x8*>(&Abuf[r * 64 + slot * 8]);
            }
            #pragma unroll
            for (int n = 0; n < 4; ++n) {
                const int r = wc * 64 + n * 16 + l15;
                const int slot = (kk * 4 + l4) ^ (r & 7);
                bF[n] = *reinterpret_cast<const bf16x8*>(&Bbuf[r * 64 + slot * 8]);
            }
            #pragma unroll
            for (int m = 0; m < 4; ++m)
                #pragma unroll
                for (int n = 0; n < 4; ++n)
                    acc[m][n] = __builtin_amdgcn_mfma_f32_16x16x32_bf16(aF[m], bF[n], acc[m][n], 0, 0, 0);
        }
        __syncthreads();   // before next k-step overwrites LDS
    }

    // Epilogue. C/D mapping: col = lane&15, row = (lane>>4)*4 + reg.
    if (tid < TILE) { rowsum[tid] = 0.0f; colsum[tid] = 0.0f; }
    __syncthreads();

    float cs[4] = {0.0f, 0.0f, 0.0f, 0.0f};   // per-n column partials (col = l15 fixed)
    #pragma unroll
    for (int m = 0; m < 4; ++m) {
        #pragma unroll
        for (int r = 0; r < 4; ++r) {
            const int row_l = wr * 64 + m * 16 + l4 * 4 + r;
            const int grow = rowBase + row_l;
            const int prow = grow < HALF_N ? grow + HALF_N : grow - HALF_N;
            float p = 0.0f;
            #pragma unroll
            for (int n = 0; n < 4; ++n) {
                const int gcol = colBase + wc * 64 + n * 16 + l15;
                const float s = acc[m][n][r] * TEMP_INV;
                const float e = (gcol != grow) ? __expf(s) : 0.0f;
                p += e;
                cs[n] += e;
                if (gcol == prow) {            // strictly upper-triangle only
                    poslogit[grow] = s;
                    poslogit[gcol] = s;        // mirrored entry (pos involution)
                }
            }
            // reduce across the 16 lanes sharing this row (low-4 lane bits)
            p += __shfl_xor(p, 1);
            p += __shfl_xor(p, 2);
            p += __shfl_xor(p, 4);
            p += __shfl_xor(p, 8);
            if (l15 == 0) atomicAdd(&rowsum[row_l], p);   // LDS atomic
        }
    }
    if (offdiag) {
        #pragma unroll
        for (int n = 0; n < 4; ++n) {
            float c = cs[n];
            c += __shfl_xor(c, 16);
            c += __shfl_xor(c, 32);
            if (l4 == 0) atomicAdd(&colsum[wc * 64 + n * 16 + l15], c);
        }
    }
    __syncthreads();
    if (tid < TILE) {
        atomicAdd(&sumexp[rowBase + tid], rowsum[tid]);            // 1 global atomic/row/block
        if (offdiag) atomicAdd(&sumexp[colBase + tid], colsum[tid]); // transposed contribution
    }
}

// Kernel 3: loss = sum_i log(sumexp_i) - poslogit_i
__global__ __launch_bounds__(256) void finalize_kernel(const float* __restrict__ sumexp,
                                                       const float* __restrict__ poslogit,
                                                       float* __restrict__ out) {
    const int i = blockIdx.x * 256 + threadIdx.x;
    float li = logf(sumexp[i]) - poslogit[i];
    #pragma unroll
    for (int off = 32; off >= 1; off >>= 1) li += __shfl_xor(li, off);
    __shared__ float wss[4];
    if ((threadIdx.x & 63) == 0) wss[threadIdx.x >> 6] = li;
    __syncthreads();
    if (threadIdx.x == 0) atomicAdd(out, wss[0] + wss[1] + wss[2] + wss[3]);
}

extern "C" void kernel_launch(void* const* d_in, const int* in_sizes, int n_in,
                              void* d_out, int out_size, void* d_ws, size_t ws_size,
                              hipStream_t stream) {
    const float* X = (const float*)d_in[0];
    float* out = (float*)d_out;

    unsigned short* XN = (unsigned short*)d_ws;                       // 8 MB bf16
    float* sumexp   = (float*)((char*)d_ws + (size_t)NROWS * KD * 2); // 32 KB
    float* poslogit = sumexp + NROWS;                                 // 32 KB

    normalize_kernel<<<NROWS, 256, 0, stream>>>(X, XN, sumexp, out);
    gemm_fused_kernel<<<NTRI, 256, 0, stream>>>(XN, sumexp, poslogit);
    finalize_kernel<<<NROWS / 256, 256, 0, stream>>>(sumexp, poslogit, out);
}